// Round 2
// baseline (3237.587 us; speedup 1.0000x reference)
//
#include <hip/hip_runtime.h>
#include <hip/hip_bf16.h>
#include <math.h>

// Problem constants (from reference)
#define BB 64
#define TT 2048
#define VV 4096
#define EE 128
#define H2 128
#define SS 8
#define CC 2
#define NG 1024   // 2 dirs * 4*H2 gate columns in combined EG table

__device__ __forceinline__ float sigf(float x) { return 1.f / (1.f + __expf(-x)); }
__device__ __forceinline__ float tanh_fast(float x) { return 1.f - 2.f / (__expf(2.f * x) + 1.f); }

// ---------------------------------------------------------------------------
// Kernel 1: EG[v, n] = sum_k emb[v,k] * W_comb[n,k] + b_comb[n]
// W_comb rows 0..511 = W_ih_f, rows 512..1023 = W_ih_b. fp32 tiled GEMM.
// ---------------------------------------------------------------------------
__global__ __launch_bounds__(256) void eg_gemm(
    const float* __restrict__ emb,
    const float* __restrict__ Wf, const float* __restrict__ bf,
    const float* __restrict__ Wb, const float* __restrict__ bb,
    float* __restrict__ EG)
{
    __shared__ float As[64][68];
    __shared__ float Bs[64][68];

    const int tid = threadIdx.x;
    const int tx = tid & 15, ty = tid >> 4;
    const int m0 = blockIdx.y * 64;
    const int n0 = blockIdx.x * 64;

    const float* Bsrc;
    const float* bias;
    if (n0 < 512) { Bsrc = Wf + n0 * EE; bias = bf + n0; }
    else          { Bsrc = Wb + (n0 - 512) * EE; bias = bb + (n0 - 512); }

    float acc[4][4] = {};

    for (int kc = 0; kc < 2; ++kc) {
        for (int c = tid; c < 1024; c += 256) {
            int r = c >> 4, q = c & 15;
            float4 av = *(const float4*)(emb + (size_t)(m0 + r) * EE + kc * 64 + q * 4);
            As[q * 4 + 0][r] = av.x; As[q * 4 + 1][r] = av.y;
            As[q * 4 + 2][r] = av.z; As[q * 4 + 3][r] = av.w;
            float4 bv = *(const float4*)(Bsrc + (size_t)r * EE + kc * 64 + q * 4);
            Bs[q * 4 + 0][r] = bv.x; Bs[q * 4 + 1][r] = bv.y;
            Bs[q * 4 + 2][r] = bv.z; Bs[q * 4 + 3][r] = bv.w;
        }
        __syncthreads();
        #pragma unroll 8
        for (int k = 0; k < 64; ++k) {
            float4 a4 = *(const float4*)&As[k][4 * ty];
            float4 b4 = *(const float4*)&Bs[k][4 * tx];
            float a[4] = {a4.x, a4.y, a4.z, a4.w};
            float b[4] = {b4.x, b4.y, b4.z, b4.w};
            #pragma unroll
            for (int i = 0; i < 4; ++i)
                #pragma unroll
                for (int jn = 0; jn < 4; ++jn)
                    acc[i][jn] = fmaf(a[i], b[jn], acc[i][jn]);
        }
        __syncthreads();
    }

    #pragma unroll
    for (int i = 0; i < 4; ++i) {
        int m = m0 + 4 * ty + i;
        #pragma unroll
        for (int jn = 0; jn < 4; ++jn) {
            int nn = 4 * tx + jn;
            EG[(size_t)m * NG + n0 + nn] = acc[i][jn] + bias[nn];
        }
    }
}

// ---------------------------------------------------------------------------
// Kernel 2: fused LSTM recurrence + ragged segment max-pool.
// grid = 128 blocks: block (b, dir). 256 threads = 4 waves, 1 wave/SIMD.
// Lane tid<128  : owns W_hh rows (i_u, f_u), u = tid.    Holds c_u, pooling.
// Lane tid>=128 : owns W_hh rows (g_u, o_u), u = tid-128.
// Weight rows live in 256 VGPRs/lane. h broadcast via v_readlane (VALU pipe),
// NOT ds_read broadcast (LDS pipe was the round-1 bottleneck).
// ---------------------------------------------------------------------------
__global__ __launch_bounds__(256, 1) void lstm_rec(
    const int* __restrict__ sentence, const int* __restrict__ lens,
    const float* __restrict__ Whhf, const float* __restrict__ Whhb,
    const float* __restrict__ EG, float* __restrict__ pws)
{
    const int bid = blockIdx.x;
    const int b = bid >> 1;
    const int dir = bid & 1;            // 0 = forward, 1 = backward
    const int tid = threadIdx.x;
    const int l = tid & 63;             // lane in wave
    const int u = tid & 127;            // hidden unit index
    const bool lohalf = tid < 128;      // owns (i,f) + cell state
    const int L = lens[b];
    const int* __restrict__ srow = sentence + (size_t)b * TT;

    // rows of W_hh this lane owns
    const int r0 = lohalf ? u : (256 + u);
    const int r1 = r0 + 128;
    const float* __restrict__ Wh = (dir == 0 ? Whhf : Whhb);

    float w0[128], w1[128];
    #pragma unroll
    for (int k4 = 0; k4 < 32; ++k4) {
        float4 a = *(const float4*)(Wh + (size_t)r0 * H2 + 4 * k4);
        w0[4 * k4 + 0] = a.x; w0[4 * k4 + 1] = a.y;
        w0[4 * k4 + 2] = a.z; w0[4 * k4 + 3] = a.w;
        float4 bq = *(const float4*)(Wh + (size_t)r1 * H2 + 4 * k4);
        w1[4 * k4 + 0] = bq.x; w1[4 * k4 + 1] = bq.y;
        w1[4 * k4 + 2] = bq.z; w1[4 * k4 + 3] = bq.w;
    }

    __shared__ float h_lds[128];
    __shared__ float tg_lds[128];   // tanh(g) from upper half
    __shared__ float so_lds[128];   // sig(o)  from upper half
    if (lohalf) h_lds[u] = 0.f;

    const int cb = dir * 512;           // EG column base for this direction
    const int col0 = cb + r0, col1 = cb + r1;

    float c = 0.f;
    float pm = -INFINITY;

    const int wseg = (L + SS - 1) >> 3;
    const bool haspad = (SS * wseg > L);
    const int padlo = L / wseg;
    int cur_seg = dir ? (SS - 1) : 0;
    int nb = dir ? (SS - 1) * wseg : wseg;

    // --- preload xv for t=0, token for t=1 ---
    int tt0 = dir ? (L - 1) : 0;
    int tok = srow[tt0];
    float xv0 = EG[(size_t)tok * NG + col0];
    float xv1 = EG[(size_t)tok * NG + col1];
    int t1p = dir ? (L - 2) : 1;
    t1p = max(0, min(TT - 1, t1p));
    int tok_nxt = srow[t1p];

    __syncthreads();                    // h_lds init visible
    float h_a = h_lds[l];
    float h_b = h_lds[64 + l];

    for (int t = 0; t < L; ++t) {
        // ---- dot: acc = W_hh[row] . h, h broadcast via readlane ----
        float acc0 = 0.f, acc1 = 0.f;
        #pragma unroll
        for (int k = 0; k < 64; ++k) {
            float hk = __int_as_float(__builtin_amdgcn_readlane(__float_as_int(h_a), k));
            acc0 = fmaf(w0[k], hk, acc0);
            acc1 = fmaf(w1[k], hk, acc1);
        }
        #pragma unroll
        for (int k = 0; k < 64; ++k) {
            float hk = __int_as_float(__builtin_amdgcn_readlane(__float_as_int(h_b), k));
            acc0 = fmaf(w0[64 + k], hk, acc0);
            acc1 = fmaf(w1[64 + k], hk, acc1);
        }
        float g0 = acc0 + xv0;          // xv prefetched last iter (latency covered)
        float g1 = acc1 + xv1;

        // ---- prefetch xv for t+1, token for t+2 ----
        float nxv0 = EG[(size_t)tok_nxt * NG + col0];
        float nxv1 = EG[(size_t)tok_nxt * NG + col1];
        int t2p = dir ? (L - 3 - t) : (t + 2);
        t2p = max(0, min(TT - 1, t2p));
        tok_nxt = srow[t2p];

        // ---- upper half: activations of g,o ----
        if (!lohalf) {
            tg_lds[u] = tanh_fast(g0);
            so_lds[u] = sigf(g1);
        }
        __syncthreads();

        // ---- lower half: cell/h update + pooling ----
        if (lohalf) {
            float tg = tg_lds[u];
            float so = so_lds[u];
            c = sigf(g1) * c + sigf(g0) * tg;
            float hn = so * tanh_fast(c);

            const int tt = dir ? (L - 1 - t) : t;
            bool bnd = dir ? (tt < nb) : (tt >= nb);
            if (bnd) {
                float v = pm;
                if (haspad && cur_seg >= padlo) v = fmaxf(v, 0.f);
                pws[(((size_t)b * 2 + dir) * SS + cur_seg) * H2 + u] = v;
                pm = -INFINITY;
                cur_seg += dir ? -1 : 1;
                nb += dir ? -wseg : wseg;
            }
            pm = fmaxf(pm, hn);
            h_lds[u] = hn;
        }
        __syncthreads();

        h_a = h_lds[l];
        h_b = h_lds[64 + l];
        xv0 = nxv0; xv1 = nxv1;
    }

    if (lohalf) {
        float v = pm;
        if (haspad && cur_seg >= padlo) v = fmaxf(v, 0.f);
        pws[(((size_t)b * 2 + dir) * SS + cur_seg) * H2 + u] = v;
    }
}

// ---------------------------------------------------------------------------
// Kernel 3: out[b,c] = b_dense[c] + sum_k flat[b,k] * W_dense[c,k]
// ---------------------------------------------------------------------------
__global__ __launch_bounds__(256) void dense_k(
    const float* __restrict__ pws, const float* __restrict__ Wd,
    const float* __restrict__ bd, float* __restrict__ out)
{
    const int b = blockIdx.x;
    const int tid = threadIdx.x;
    float a0 = 0.f, a1 = 0.f;
    for (int k = tid; k < 2048; k += 256) {
        int h = k >> 3, s = k & 7;
        int dir = h >> 7, j = h & 127;
        float v = pws[(((size_t)b * 2 + dir) * SS + s) * H2 + j];
        a0 = fmaf(v, Wd[k], a0);
        a1 = fmaf(v, Wd[2048 + k], a1);
    }
    __shared__ float r0[256], r1[256];
    r0[tid] = a0; r1[tid] = a1;
    __syncthreads();
    for (int s = 128; s > 0; s >>= 1) {
        if (tid < s) { r0[tid] += r0[tid + s]; r1[tid] += r1[tid + s]; }
        __syncthreads();
    }
    if (tid == 0) {
        out[b * 2 + 0] = r0[0] + bd[0];
        out[b * 2 + 1] = r1[0] + bd[1];
    }
}

// ---------------------------------------------------------------------------
extern "C" void kernel_launch(void* const* d_in, const int* in_sizes, int n_in,
                              void* d_out, int out_size, void* d_ws, size_t ws_size,
                              hipStream_t stream)
{
    const int*   sentence = (const int*)d_in[0];
    const int*   lens     = (const int*)d_in[1];
    const float* emb      = (const float*)d_in[2];
    const float* Wihf     = (const float*)d_in[3];
    const float* Whhf     = (const float*)d_in[4];
    const float* bf       = (const float*)d_in[5];
    const float* Wihb     = (const float*)d_in[6];
    const float* Whhb     = (const float*)d_in[7];
    const float* bb       = (const float*)d_in[8];
    const float* Wd       = (const float*)d_in[9];
    const float* bd       = (const float*)d_in[10];
    float* out = (float*)d_out;

    float* EG  = (float*)d_ws;                    // [4096][1024] fp32 = 16 MB
    float* pws = EG + (size_t)VV * NG;            // [64][2][8][128] fp32 = 512 KB

    eg_gemm<<<dim3(16, 64), 256, 0, stream>>>(emb, Wihf, bf, Wihb, bb, EG);
    lstm_rec<<<128, 256, 0, stream>>>(sentence, lens, Whhf, Whhb, EG, pws);
    dense_k<<<64, 256, 0, stream>>>(pws, Wd, bd, out);
}

// Round 3
// 2071.429 us; speedup vs baseline: 1.5630x; 1.5630x over previous
//
#include <hip/hip_runtime.h>
#include <hip/hip_bf16.h>
#include <math.h>

// Problem constants (from reference)
#define BB 64
#define TT 2048
#define VV 4096
#define EE 128
#define H2 128
#define SS 8
#define CC 2
#define NG 1024   // 2 dirs * 4*H2 gate columns in combined EG table

typedef _Float16 h2f __attribute__((ext_vector_type(2)));

__device__ __forceinline__ float sigf(float x) { return 1.f / (1.f + __expf(-x)); }
__device__ __forceinline__ float tanh_fast(float x) { return 1.f - 2.f / (__expf(2.f * x) + 1.f); }

__device__ __forceinline__ float dot2acc(h2f w, h2f h, float acc) {
#if __has_builtin(__builtin_amdgcn_fdot2)
    return __builtin_amdgcn_fdot2(w, h, acc, false);
#else
    return fmaf((float)w.x, (float)h.x, fmaf((float)w.y, (float)h.y, acc));
#endif
}

// ---------------------------------------------------------------------------
// Kernel 1: EG[v, n] = sum_k emb[v,k] * W_comb[n,k] + b_comb[n]   (fp32 GEMM)
// ---------------------------------------------------------------------------
__global__ __launch_bounds__(256) void eg_gemm(
    const float* __restrict__ emb,
    const float* __restrict__ Wf, const float* __restrict__ bf,
    const float* __restrict__ Wb, const float* __restrict__ bb,
    float* __restrict__ EG)
{
    __shared__ float As[64][68];
    __shared__ float Bs[64][68];

    const int tid = threadIdx.x;
    const int tx = tid & 15, ty = tid >> 4;
    const int m0 = blockIdx.y * 64;
    const int n0 = blockIdx.x * 64;

    const float* Bsrc;
    const float* bias;
    if (n0 < 512) { Bsrc = Wf + n0 * EE; bias = bf + n0; }
    else          { Bsrc = Wb + (n0 - 512) * EE; bias = bb + (n0 - 512); }

    float acc[4][4] = {};

    for (int kc = 0; kc < 2; ++kc) {
        for (int c = tid; c < 1024; c += 256) {
            int r = c >> 4, q = c & 15;
            float4 av = *(const float4*)(emb + (size_t)(m0 + r) * EE + kc * 64 + q * 4);
            As[q * 4 + 0][r] = av.x; As[q * 4 + 1][r] = av.y;
            As[q * 4 + 2][r] = av.z; As[q * 4 + 3][r] = av.w;
            float4 bv = *(const float4*)(Bsrc + (size_t)r * EE + kc * 64 + q * 4);
            Bs[q * 4 + 0][r] = bv.x; Bs[q * 4 + 1][r] = bv.y;
            Bs[q * 4 + 2][r] = bv.z; Bs[q * 4 + 3][r] = bv.w;
        }
        __syncthreads();
        #pragma unroll 8
        for (int k = 0; k < 64; ++k) {
            float4 a4 = *(const float4*)&As[k][4 * ty];
            float4 b4 = *(const float4*)&Bs[k][4 * tx];
            float a[4] = {a4.x, a4.y, a4.z, a4.w};
            float b[4] = {b4.x, b4.y, b4.z, b4.w};
            #pragma unroll
            for (int i = 0; i < 4; ++i)
                #pragma unroll
                for (int jn = 0; jn < 4; ++jn)
                    acc[i][jn] = fmaf(a[i], b[jn], acc[i][jn]);
        }
        __syncthreads();
    }

    #pragma unroll
    for (int i = 0; i < 4; ++i) {
        int m = m0 + 4 * ty + i;
        #pragma unroll
        for (int jn = 0; jn < 4; ++jn) {
            int nn = 4 * tx + jn;
            EG[(size_t)m * NG + n0 + nn] = acc[i][jn] + bias[nn];
        }
    }
}

// ---------------------------------------------------------------------------
// Kernel 2: fused LSTM recurrence + ragged segment max-pool.
// grid = 128 blocks (b,dir). 256 threads = 4 waves, 1 wave/SIMD.
// tid<128 owns rows (i_u, f_u) + cell state; tid>=128 owns (g_u, o_u).
// W_hh rows held as packed-f16 pairs: 128 ARCH VGPRs/lane (no AGPR spill).
// h broadcast: lane l holds packed (h[2l],h[2l+1]) f16; dot uses
// v_readlane + v_dot2_f32_f16 (VALU pipe only — no LDS broadcast reads).
// EG gate-bias gather prefetched 2 steps ahead so the pre-barrier
// vmcnt(0) drain finds loads complete.
// ---------------------------------------------------------------------------
__global__ __launch_bounds__(256, 1) void lstm_rec(
    const int* __restrict__ sentence, const int* __restrict__ lens,
    const float* __restrict__ Whhf, const float* __restrict__ Whhb,
    const float* __restrict__ EG, float* __restrict__ pws)
{
    const int bid = blockIdx.x;
    const int b = bid >> 1;
    const int dir = bid & 1;            // 0 = forward, 1 = backward
    const int tid = threadIdx.x;
    const int l = tid & 63;             // lane in wave
    const int u = tid & 127;            // hidden unit index
    const bool lohalf = tid < 128;      // owns (i,f) + cell state
    const int L = lens[b];
    const int* __restrict__ srow = sentence + (size_t)b * TT;

    const int r0 = lohalf ? u : (256 + u);
    const int r1 = r0 + 128;
    const float* __restrict__ Wh = (dir == 0 ? Whhf : Whhb);

    // --- W_hh rows -> packed f16 pairs, 64+64 arch VGPRs ---
    h2f w0[64], w1[64];
    #pragma unroll
    for (int k4 = 0; k4 < 32; ++k4) {
        float4 a = *(const float4*)(Wh + (size_t)r0 * H2 + 4 * k4);
        w0[2 * k4 + 0].x = (_Float16)a.x; w0[2 * k4 + 0].y = (_Float16)a.y;
        w0[2 * k4 + 1].x = (_Float16)a.z; w0[2 * k4 + 1].y = (_Float16)a.w;
        float4 bq = *(const float4*)(Wh + (size_t)r1 * H2 + 4 * k4);
        w1[2 * k4 + 0].x = (_Float16)bq.x; w1[2 * k4 + 0].y = (_Float16)bq.y;
        w1[2 * k4 + 1].x = (_Float16)bq.z; w1[2 * k4 + 1].y = (_Float16)bq.w;
    }

    __shared__ int hpack[64];           // packed f16 h pairs
    __shared__ float tg_lds[128];       // tanh(g) from upper half
    __shared__ float so_lds[128];       // sig(o)  from upper half
    if (tid < 64) hpack[tid] = 0;

    const int cb = dir * 512;
    const int col0 = cb + r0, col1 = cb + r1;

    float c = 0.f;
    float pm = -INFINITY;

    const int wseg = (L + SS - 1) >> 3;
    const bool haspad = (SS * wseg > L);
    const int padlo = L / wseg;
    int cur_seg = dir ? (SS - 1) : 0;
    int nb = dir ? (SS - 1) * wseg : wseg;

    // --- prefetch: xv for t=0 and t=1 in flight; token for t=2 staged ---
    int i0 = dir ? (L - 1) : 0;
    int tok0 = srow[i0];
    float xv0_cur = EG[(size_t)tok0 * NG + col0];
    float xv1_cur = EG[(size_t)tok0 * NG + col1];
    int i1 = dir ? (L - 2) : 1;  i1 = max(0, min(TT - 1, i1));
    int tok1 = srow[i1];
    float xv0_n = EG[(size_t)tok1 * NG + col0];
    float xv1_n = EG[(size_t)tok1 * NG + col1];
    int i2 = dir ? (L - 3) : 2;  i2 = max(0, min(TT - 1, i2));
    int tok2 = srow[i2];

    __syncthreads();                    // hpack init visible
    int hp = hpack[l];

    for (int t = 0; t < L; ++t) {
        // ---- issue EG gather for step t+2 (2-step latency cover) ----
        float p0 = EG[(size_t)tok2 * NG + col0];
        float p1 = EG[(size_t)tok2 * NG + col1];
        int i3 = dir ? (L - 4 - t) : (t + 3);
        i3 = max(0, min(TT - 1, i3));
        tok2 = srow[i3];

        // ---- dot: 64 readlane + 128 v_dot2_f32_f16 ----
        float acc0 = 0.f, acc1 = 0.f;
        #pragma unroll
        for (int k = 0; k < 64; ++k) {
            int hk = __builtin_amdgcn_readlane(hp, k);
            h2f hv = __builtin_bit_cast(h2f, hk);
            acc0 = dot2acc(w0[k], hv, acc0);
            acc1 = dot2acc(w1[k], hv, acc1);
        }
        float g0 = acc0 + xv0_cur;
        float g1 = acc1 + xv1_cur;

        // ---- upper half publishes activations of g,o ----
        if (!lohalf) {
            tg_lds[u] = tanh_fast(g0);
            so_lds[u] = sigf(g1);
        }
        __syncthreads();

        // ---- lower half: cell/h update + pooling + h republish (f16) ----
        if (lohalf) {
            float tg = tg_lds[u];
            float so = so_lds[u];
            c = sigf(g1) * c + sigf(g0) * tg;
            float hn = so * tanh_fast(c);

            const int tt = dir ? (L - 1 - t) : t;
            bool bnd = dir ? (tt < nb) : (tt >= nb);
            if (bnd) {
                float v = pm;
                if (haspad && cur_seg >= padlo) v = fmaxf(v, 0.f);
                pws[(((size_t)b * 2 + dir) * SS + cur_seg) * H2 + u] = v;
                pm = -INFINITY;
                cur_seg += dir ? -1 : 1;
                nb += dir ? -wseg : wseg;
            }
            pm = fmaxf(pm, hn);
            ((_Float16*)hpack)[u] = (_Float16)hn;
        }
        __syncthreads();

        hp = hpack[l];
        xv0_cur = xv0_n; xv1_cur = xv1_n;
        xv0_n = p0;      xv1_n = p1;
    }

    if (lohalf) {
        float v = pm;
        if (haspad && cur_seg >= padlo) v = fmaxf(v, 0.f);
        pws[(((size_t)b * 2 + dir) * SS + cur_seg) * H2 + u] = v;
    }
}

// ---------------------------------------------------------------------------
// Kernel 3: out[b,c] = b_dense[c] + sum_k flat[b,k] * W_dense[c,k]
// ---------------------------------------------------------------------------
__global__ __launch_bounds__(256) void dense_k(
    const float* __restrict__ pws, const float* __restrict__ Wd,
    const float* __restrict__ bd, float* __restrict__ out)
{
    const int b = blockIdx.x;
    const int tid = threadIdx.x;
    float a0 = 0.f, a1 = 0.f;
    for (int k = tid; k < 2048; k += 256) {
        int h = k >> 3, s = k & 7;
        int dir = h >> 7, j = h & 127;
        float v = pws[(((size_t)b * 2 + dir) * SS + s) * H2 + j];
        a0 = fmaf(v, Wd[k], a0);
        a1 = fmaf(v, Wd[2048 + k], a1);
    }
    __shared__ float r0[256], r1[256];
    r0[tid] = a0; r1[tid] = a1;
    __syncthreads();
    for (int s = 128; s > 0; s >>= 1) {
        if (tid < s) { r0[tid] += r0[tid + s]; r1[tid] += r1[tid + s]; }
        __syncthreads();
    }
    if (tid == 0) {
        out[b * 2 + 0] = r0[0] + bd[0];
        out[b * 2 + 1] = r1[0] + bd[1];
    }
}

// ---------------------------------------------------------------------------
extern "C" void kernel_launch(void* const* d_in, const int* in_sizes, int n_in,
                              void* d_out, int out_size, void* d_ws, size_t ws_size,
                              hipStream_t stream)
{
    const int*   sentence = (const int*)d_in[0];
    const int*   lens     = (const int*)d_in[1];
    const float* emb      = (const float*)d_in[2];
    const float* Wihf     = (const float*)d_in[3];
    const float* Whhf     = (const float*)d_in[4];
    const float* bf       = (const float*)d_in[5];
    const float* Wihb     = (const float*)d_in[6];
    const float* Whhb     = (const float*)d_in[7];
    const float* bb       = (const float*)d_in[8];
    const float* Wd       = (const float*)d_in[9];
    const float* bd       = (const float*)d_in[10];
    float* out = (float*)d_out;

    float* EG  = (float*)d_ws;                    // [4096][1024] fp32 = 16 MB
    float* pws = EG + (size_t)VV * NG;            // [64][2][8][128] fp32 = 512 KB

    eg_gemm<<<dim3(16, 64), 256, 0, stream>>>(emb, Wihf, bf, Wihb, bb, EG);
    lstm_rec<<<128, 256, 0, stream>>>(sentence, lens, Whhf, Whhb, EG, pws);
    dense_k<<<64, 256, 0, stream>>>(pws, Wd, bd, out);
}

// Round 4
// 1548.401 us; speedup vs baseline: 2.0909x; 1.3378x over previous
//
#include <hip/hip_runtime.h>
#include <hip/hip_bf16.h>
#include <math.h>

// Problem constants (from reference)
#define BB 64
#define TT 2048
#define VV 4096
#define EE 128
#define H2 128
#define SS 8
#define CC 2

typedef _Float16 h2f __attribute__((ext_vector_type(2)));

__device__ __forceinline__ float sigf(float x) { return 1.f / (1.f + __expf(-x)); }
__device__ __forceinline__ float tanh_fast(float x) { return 1.f - 2.f / (__expf(2.f * x) + 1.f); }

__device__ __forceinline__ float dot2acc(h2f w, h2f h, float acc) {
#if __has_builtin(__builtin_amdgcn_fdot2)
    return __builtin_amdgcn_fdot2(w, h, acc, false);
#else
    return fmaf((float)w.x, (float)h.x, fmaf((float)w.y, (float)h.y, acc));
#endif
}

// ---------------------------------------------------------------------------
// Kernel 1: EG gate-bias table, PAIR layout for the recurrence:
//   EGp[v][d][p] = float2{ gate rA(p), gate rB(p) },  p in [0,256)
//   p<128  : rA = p       (i_u, u=p),    rB = 128+p (f_u)
//   p>=128 : rA = 128+p   (g_u, u=p-128), rB = 256+p (o_u)
// i.e. gate row r of dir d lands at p=(r&127)+(r>=256?128:0), slot=(r>>7)&1.
// ---------------------------------------------------------------------------
__global__ __launch_bounds__(256) void eg_gemm(
    const float* __restrict__ emb,
    const float* __restrict__ Wf, const float* __restrict__ bf,
    const float* __restrict__ Wb, const float* __restrict__ bb,
    float* __restrict__ EGp)
{
    __shared__ float As[64][68];
    __shared__ float Bs[64][68];

    const int tid = threadIdx.x;
    const int tx = tid & 15, ty = tid >> 4;
    const int m0 = blockIdx.y * 64;
    const int n0 = blockIdx.x * 64;

    const float* Bsrc;
    const float* bias;
    if (n0 < 512) { Bsrc = Wf + n0 * EE; bias = bf + n0; }
    else          { Bsrc = Wb + (n0 - 512) * EE; bias = bb + (n0 - 512); }

    float acc[4][4] = {};

    for (int kc = 0; kc < 2; ++kc) {
        for (int c = tid; c < 1024; c += 256) {
            int r = c >> 4, q = c & 15;
            float4 av = *(const float4*)(emb + (size_t)(m0 + r) * EE + kc * 64 + q * 4);
            As[q * 4 + 0][r] = av.x; As[q * 4 + 1][r] = av.y;
            As[q * 4 + 2][r] = av.z; As[q * 4 + 3][r] = av.w;
            float4 bv = *(const float4*)(Bsrc + (size_t)r * EE + kc * 64 + q * 4);
            Bs[q * 4 + 0][r] = bv.x; Bs[q * 4 + 1][r] = bv.y;
            Bs[q * 4 + 2][r] = bv.z; Bs[q * 4 + 3][r] = bv.w;
        }
        __syncthreads();
        #pragma unroll 8
        for (int k = 0; k < 64; ++k) {
            float4 a4 = *(const float4*)&As[k][4 * ty];
            float4 b4 = *(const float4*)&Bs[k][4 * tx];
            float a[4] = {a4.x, a4.y, a4.z, a4.w};
            float b[4] = {b4.x, b4.y, b4.z, b4.w};
            #pragma unroll
            for (int i = 0; i < 4; ++i)
                #pragma unroll
                for (int jn = 0; jn < 4; ++jn)
                    acc[i][jn] = fmaf(a[i], b[jn], acc[i][jn]);
        }
        __syncthreads();
    }

    #pragma unroll
    for (int i = 0; i < 4; ++i) {
        int m = m0 + 4 * ty + i;                 // vocab index v
        #pragma unroll
        for (int jn = 0; jn < 4; ++jn) {
            int nn = 4 * tx + jn;
            int n = n0 + nn;                     // combined gate col
            int d = n >> 9;
            int r = n & 511;
            int slot = (r >> 7) & 1;
            int p = (r & 127) + (r >= 256 ? 128 : 0);
            EGp[(((size_t)m * 2 + d) * 256 + p) * 2 + slot] = acc[i][jn] + bias[nn];
        }
    }
}

// ---------------------------------------------------------------------------
// Kernel 2: fused LSTM recurrence + ragged segment max-pool.
// grid = 128 blocks (b,dir). 256 threads = 4 waves, 1 wave/SIMD.
// Wave w, lane l: unit u = w*32 + (l>>1).
//   even lane: W_hh rows (i_u, f_u); odd lane: rows (g_u, o_u).
// Gate combine via 2x shfl_xor(1) (intra-wave, no barrier).
// h published once per step: ds_write_b16 -> ONE __syncthreads -> ds_read_b32,
// double-buffered. EG pair gathered as one dwordx2/lane, 2 steps ahead.
// ---------------------------------------------------------------------------
__global__ __launch_bounds__(256, 1) void lstm_rec(
    const int* __restrict__ sentence, const int* __restrict__ lens,
    const float* __restrict__ Whhf, const float* __restrict__ Whhb,
    const float* __restrict__ EGp, float* __restrict__ pws)
{
    const int bid = blockIdx.x;
    const int b = bid >> 1;
    const int dir = bid & 1;            // 0 = forward, 1 = backward
    const int tid = threadIdx.x;
    const int l = tid & 63;             // lane in wave
    const int wv = tid >> 6;            // wave 0..3
    const int u = wv * 32 + (l >> 1);   // hidden unit this lane pair covers
    const bool evn = (l & 1) == 0;      // even lane: (i,f) + cell state
    const int L = lens[b];
    const int* __restrict__ srow = sentence + (size_t)b * TT;

    // rows of W_hh this lane owns (i/f on even, g/o on odd)
    const int r0 = evn ? u : (256 + u);
    const int r1 = r0 + 128;
    const float* __restrict__ Wh = (dir == 0 ? Whhf : Whhb);

    // --- W_hh rows -> packed f16 pairs: 128 arch VGPRs ---
    h2f w0[64], w1[64];
    #pragma unroll
    for (int k4 = 0; k4 < 32; ++k4) {
        float4 a = *(const float4*)(Wh + (size_t)r0 * H2 + 4 * k4);
        w0[2 * k4 + 0].x = (_Float16)a.x; w0[2 * k4 + 0].y = (_Float16)a.y;
        w0[2 * k4 + 1].x = (_Float16)a.z; w0[2 * k4 + 1].y = (_Float16)a.w;
        float4 bq = *(const float4*)(Wh + (size_t)r1 * H2 + 4 * k4);
        w1[2 * k4 + 0].x = (_Float16)bq.x; w1[2 * k4 + 0].y = (_Float16)bq.y;
        w1[2 * k4 + 1].x = (_Float16)bq.z; w1[2 * k4 + 1].y = (_Float16)bq.w;
    }

    __shared__ int hpk[2][64];          // double-buffered packed f16 h pairs
    if (tid < 64) hpk[0][tid] = 0;

    // per-lane EG pair column
    const int p = evn ? u : (128 + u);
    const float2* __restrict__ egp = (const float2*)EGp;
    // element index for token v: (v*2+dir)*256 + p

    float c = 0.f;
    float pm = -INFINITY;

    const int wseg = (L + SS - 1) >> 3;
    const bool haspad = (SS * wseg > L);
    const int padlo = L / wseg;
    int cur_seg = dir ? (SS - 1) : 0;
    int nb = dir ? (SS - 1) * wseg : wseg;

    // --- prefetch pipeline: xv for t=0,1 in flight; token for t=2 staged ---
    int i0 = dir ? (L - 1) : 0;
    int tok0 = srow[i0];
    float2 xv_cur = egp[((size_t)tok0 * 2 + dir) * 256 + p];
    int i1 = dir ? (L - 2) : 1;  i1 = max(0, min(TT - 1, i1));
    int tok1 = srow[i1];
    float2 xv_nxt = egp[((size_t)tok1 * 2 + dir) * 256 + p];
    int i2 = dir ? (L - 3) : 2;  i2 = max(0, min(TT - 1, i2));
    int tok2 = srow[i2];

    __syncthreads();                    // hpk[0] init visible

    for (int t = 0; t < L; ++t) {
        const int buf = t & 1;
        // ---- h for this step (written before the previous barrier) ----
        int hp = hpk[buf][l];

        // ---- issue EG gather for step t+2 (drained at NEXT barrier) ----
        float2 pf = egp[((size_t)tok2 * 2 + dir) * 256 + p];
        int i3 = dir ? (L - 4 - t) : (t + 3);
        i3 = max(0, min(TT - 1, i3));
        tok2 = srow[i3];

        // ---- dot: 64 readlane + 128 v_dot2_f32_f16 ----
        float acc0 = 0.f, acc1 = 0.f;
        #pragma unroll
        for (int k = 0; k < 64; ++k) {
            int hk = __builtin_amdgcn_readlane(hp, k);
            h2f hv = __builtin_bit_cast(h2f, hk);
            acc0 = dot2acc(w0[k], hv, acc0);
            acc1 = dot2acc(w1[k], hv, acc1);
        }
        float g0 = acc0 + xv_cur.x;     // even: i-preact ; odd: g-preact
        float g1 = acc1 + xv_cur.y;     // even: f-preact ; odd: o-preact

        // ---- own activations ----
        float s_own = sigf(g1);                              // sf | so
        float t_own = evn ? sigf(g0) : tanh_fast(g0);        // si | tg

        // ---- pair exchange (intra-wave, lockstep) ----
        float t_x = __shfl_xor(t_own, 1, 64);
        float s_x = __shfl_xor(s_own, 1, 64);

        // even lane: c = sf*c + si*tg ; h = so*tanh(c). (odd computes garbage)
        c = s_own * c + t_own * t_x;
        float hn = s_x * tanh_fast(c);

        // ---- pooling bookkeeping (uniform branch) ----
        const int tt = dir ? (L - 1 - t) : t;
        bool bnd = dir ? (tt < nb) : (tt >= nb);
        if (bnd) {
            if (evn) {
                float v = pm;
                if (haspad && cur_seg >= padlo) v = fmaxf(v, 0.f);
                pws[(((size_t)b * 2 + dir) * SS + cur_seg) * H2 + u] = v;
            }
            pm = -INFINITY;
            cur_seg += dir ? -1 : 1;
            nb += dir ? -wseg : wseg;
        }
        pm = fmaxf(pm, hn);

        // ---- publish h (f16) into the other buffer; single barrier ----
        if (evn) ((_Float16*)hpk[buf ^ 1])[u] = (_Float16)hn;
        __syncthreads();

        xv_cur = xv_nxt;
        xv_nxt = pf;
    }

    if (evn) {
        float v = pm;
        if (haspad && cur_seg >= padlo) v = fmaxf(v, 0.f);
        pws[(((size_t)b * 2 + dir) * SS + cur_seg) * H2 + u] = v;
    }
}

// ---------------------------------------------------------------------------
// Kernel 3: out[b,c] = b_dense[c] + sum_k flat[b,k] * W_dense[c,k]
// ---------------------------------------------------------------------------
__global__ __launch_bounds__(256) void dense_k(
    const float* __restrict__ pws, const float* __restrict__ Wd,
    const float* __restrict__ bd, float* __restrict__ out)
{
    const int b = blockIdx.x;
    const int tid = threadIdx.x;
    float a0 = 0.f, a1 = 0.f;
    for (int k = tid; k < 2048; k += 256) {
        int h = k >> 3, s = k & 7;
        int dir = h >> 7, j = h & 127;
        float v = pws[(((size_t)b * 2 + dir) * SS + s) * H2 + j];
        a0 = fmaf(v, Wd[k], a0);
        a1 = fmaf(v, Wd[2048 + k], a1);
    }
    __shared__ float r0[256], r1[256];
    r0[tid] = a0; r1[tid] = a1;
    __syncthreads();
    for (int s = 128; s > 0; s >>= 1) {
        if (tid < s) { r0[tid] += r0[tid + s]; r1[tid] += r1[tid + s]; }
        __syncthreads();
    }
    if (tid == 0) {
        out[b * 2 + 0] = r0[0] + bd[0];
        out[b * 2 + 1] = r1[0] + bd[1];
    }
}

// ---------------------------------------------------------------------------
extern "C" void kernel_launch(void* const* d_in, const int* in_sizes, int n_in,
                              void* d_out, int out_size, void* d_ws, size_t ws_size,
                              hipStream_t stream)
{
    const int*   sentence = (const int*)d_in[0];
    const int*   lens     = (const int*)d_in[1];
    const float* emb      = (const float*)d_in[2];
    const float* Wihf     = (const float*)d_in[3];
    const float* Whhf     = (const float*)d_in[4];
    const float* bf       = (const float*)d_in[5];
    const float* Wihb     = (const float*)d_in[6];
    const float* Whhb     = (const float*)d_in[7];
    const float* bb       = (const float*)d_in[8];
    const float* Wd       = (const float*)d_in[9];
    const float* bd       = (const float*)d_in[10];
    float* out = (float*)d_out;

    float* EGp = (float*)d_ws;                    // [4096][2][256][2] fp32 = 16 MB
    float* pws = EGp + (size_t)VV * 1024;         // [64][2][8][128] fp32 = 512 KB

    eg_gemm<<<dim3(16, 64), 256, 0, stream>>>(emb, Wihf, bf, Wihb, bb, EGp);
    lstm_rec<<<128, 256, 0, stream>>>(sentence, lens, Whhf, Whhb, EGp, pws);
    dense_k<<<64, 256, 0, stream>>>(pws, Wd, bd, out);
}